// Round 11
// baseline (166.888 us; speedup 1.0000x reference)
//
#include <hip/hip_runtime.h>
#include <hip/hip_fp16.h>

#define HID 512
#define GC  640
#define CC  320
#define GG  2
#define DHALF 128
#define MARGIN 0.004f
#define FB 4

typedef __attribute__((ext_vector_type(8))) _Float16 half8;
typedef __attribute__((ext_vector_type(4))) float float4v;

__global__ __launch_bounds__(256) void zero_misc(float* meanAcc, int* cnt) {
    for (int i = threadIdx.x; i < GC; i += 256) meanAcc[i] = 0.f;
    if (threadIdx.x < 2) cnt[threadIdx.x] = 0;
}

// Pack W (fp32 [640][512]) into fp16 MFMA-frag order:
// frag t=(g*320 + kk*20 + j): lane l holds W[g*320+j*16+(l&15)][kk*32+(l>>4)*8 ..+7]
// stored contiguously at Wpk + t*512 + l*8  -> B-frag load = coalesced 1KB.
__global__ __launch_bounds__(256) void pack_w(
    const float* __restrict__ W, unsigned short* __restrict__ Wpk)
{
    const int t    = blockIdx.x * 4 + (threadIdx.x >> 6);   // 0..639
    const int lane = threadIdx.x & 63;
    const int g = t / 320, rem = t % 320, kk = rem / 20, j = rem % 20;
    const int row = g * 320 + j * 16 + (lane & 15);
    const int k   = kk * 32 + (lane >> 4) * 8;
    const float* src = W + (size_t)row * HID + k;
    float4 xa = *(const float4*)src;
    float4 xb = *(const float4*)(src + 4);
    half8 h;
    h[0] = (_Float16)xa.x; h[1] = (_Float16)xa.y;
    h[2] = (_Float16)xa.z; h[3] = (_Float16)xa.w;
    h[4] = (_Float16)xb.x; h[5] = (_Float16)xb.y;
    h[6] = (_Float16)xb.z; h[7] = (_Float16)xb.w;
    *(half8*)(Wpk + (size_t)t * 512 + lane * 8) = h;
}

// Barrier-free wave-autonomous fused kernel.
// Block = 4 waves; each wave: 16 tokens x 320 codes of one group, acc[20]=80 VGPR.
// B-frags loaded per-wave from packed Wpk (1KB coalesced, L1/L2-resident, no LDS).
// A loaded from X fp32 directly (16 rows x 128B segments), cvt in-register.
// Epilogue: wave-local LDS repack (lgkmcnt only, no block barrier), then the
// proven 16-lane contiguous-20-codes reduce with coalesced gum reads.
__global__ __launch_bounds__(256, 4) void fused(
    const float* __restrict__ X, const unsigned short* __restrict__ Wpk,
    const float* __restrict__ bq, const float* __restrict__ gum,
    const float* __restrict__ cv, float* __restrict__ out,
    float* __restrict__ meanAcc, int* __restrict__ cnt,
    int* __restrict__ flags0, int* __restrict__ flags1)
{
    __shared__ float rep[4][4][328];    // [wave][token-slot][padded cols] 21KB
    __shared__ float bqs[CC];
    __shared__ float smean[CC];

    const int tid  = threadIdx.x;
    const int lane = tid & 63;
    const int wv   = tid >> 6;          // 0..3
    const int lq   = lane & 15;
    const int q    = lane >> 4;

    int bid = blockIdx.x, nwg = gridDim.x;
    int swz = ((nwg & 7) == 0) ? (bid & 7) * (nwg >> 3) + (bid >> 3) : bid;
    const int g    = swz & 1;
    const int tok0 = (swz >> 1) * 64 + wv * 16;     // wave's token base
    int* flagsg = g ? flags1 : flags0;

    for (int i = tid; i < CC; i += 256) { bqs[i] = bq[g * CC + i]; smean[i] = 0.f; }
    __syncthreads();

    // A: lane reads X[tok0+lq][kk*32 + q*8 ..+7] (fp32)
    const float* xsrc = X + (size_t)(tok0 + lq) * HID + q * 8;
    // B: packed frags for this group
    const unsigned short* bsrc = Wpk + (size_t)g * 163840 + lane * 8;

    float4v acc[20];
#pragma unroll
    for (int j = 0; j < 20; ++j) acc[j] = (float4v){0.f, 0.f, 0.f, 0.f};

    for (int ko = 0; ko < 4; ++ko) {
#pragma unroll
        for (int ki = 0; ki < 4; ++ki) {
            const int kk = ko * 4 + ki;
            float4 xa = *(const float4*)(xsrc + kk * 32);
            float4 xb = *(const float4*)(xsrc + kk * 32 + 4);
            half8 a;
            a[0] = (_Float16)xa.x; a[1] = (_Float16)xa.y;
            a[2] = (_Float16)xa.z; a[3] = (_Float16)xa.w;
            a[4] = (_Float16)xb.x; a[5] = (_Float16)xb.y;
            a[6] = (_Float16)xb.z; a[7] = (_Float16)xb.w;
            const unsigned short* bk = bsrc + kk * 10240;
#pragma unroll
            for (int j = 0; j < 20; ++j) {
                half8 b = *(const half8*)(bk + j * 512);
                acc[j] = __builtin_amdgcn_mfma_f32_16x16x32_f16(a, b, acc[j], 0, 0, 0);
            }
        }
        __syncthreads();   // drift control: keeps the 4 waves' B streams L1-coherent
    }

    // ---- epilogue (wave-local) ----
    float macc[20];
#pragma unroll
    for (int j = 0; j < 20; ++j) macc[j] = 0.f;
    const int cb = lq * 20;

    for (int r = 0; r < 4; ++r) {
        // phase A: lane (q,lq) owns token q*4+r; scatter its 20 cols
#pragma unroll
        for (int j = 0; j < 20; ++j)
            rep[wv][q][j * 16 + lq] = acc[j][r] + bqs[j * 16 + lq];
        asm volatile("s_waitcnt lgkmcnt(0)" ::: "memory");   // wave-local fence

        // phase B: lane l -> token-slot q, contiguous codes cb..cb+19
        const int tglob = tok0 + q * 4 + r;
        const float* rrow = &rep[wv][q][cb];
        const float* grow = gum + ((size_t)tglob * GG + g) * CC + cb;

        float s = 0.f;
        float b = -3.0e38f; int bi = 0; float s2 = -3.0e38f;
#pragma unroll
        for (int jj = 0; jj < 5; ++jj) {
            float4 lv = *(const float4*)(rrow + jj * 4);
            float4 gv = *(const float4*)(grow + jj * 4);
            float lf[4] = {lv.x, lv.y, lv.z, lv.w};
            float gf[4] = {gv.x, gv.y, gv.z, gv.w};
#pragma unroll
            for (int t = 0; t < 4; ++t) {
                float v = lf[t] + gf[t];
                if (v > b)       { s2 = b; b = v; bi = cb + jj * 4 + t; }
                else if (v > s2) { s2 = v; }
                s += __expf(lf[t]);
            }
        }
        // fused 4-step reduce within the 16-lane token group
#pragma unroll
        for (int m = 1; m < 16; m <<= 1) {
            float os  = __shfl_xor(s,  m, 64);
            float ob  = __shfl_xor(b,  m, 64);
            int   obi = __shfl_xor(bi, m, 64);
            float os2 = __shfl_xor(s2, m, 64);
            s += os;
            if (ob > b || (ob == b && obi < bi)) { s2 = fmaxf(os2, b); b = ob; bi = obi; }
            else                                 { s2 = fmaxf(s2, ob); }
        }
        float inv = 1.f / s;
        // second pass from LDS (keeps live regs low)
#pragma unroll
        for (int jj = 0; jj < 5; ++jj) {
            float4 lv = *(const float4*)(rrow + jj * 4);
            macc[jj*4+0] += __expf(lv.x) * inv;
            macc[jj*4+1] += __expf(lv.y) * inv;
            macc[jj*4+2] += __expf(lv.z) * inv;
            macc[jj*4+3] += __expf(lv.w) * inv;
        }

        if (lq == 0 && (b - s2) < MARGIN) {
            int p = atomicAdd(&cnt[g], 1);
            flagsg[p] = tglob;
        }
        const float* cvp = cv + ((size_t)(g * CC + bi)) * DHALF + lq * 8;
        float4 c0v = *(const float4*)cvp;
        float4 c1v = *(const float4*)(cvp + 4);
        float* op = out + (size_t)tglob * 256 + g * DHALF + lq * 8;
        *(float4*)op       = c0v;
        *(float4*)(op + 4) = c1v;
        asm volatile("s_waitcnt lgkmcnt(0)" ::: "memory");   // reads done before overwrite
    }

    // fold macc across token-slots (q), then block smean, then global
#pragma unroll
    for (int j = 0; j < 20; ++j) {
        macc[j] += __shfl_xor(macc[j], 16, 64);
        macc[j] += __shfl_xor(macc[j], 32, 64);
    }
    if (lane < 16) {
#pragma unroll
        for (int j = 0; j < 20; ++j)
            atomicAdd(&smean[cb + j], macc[j]);
    }
    __syncthreads();
    for (int i = tid; i < CC; i += 256)
        atomicAdd(&meanAcc[g * CC + i], smean[i]);
}

// Exact fp32 recompute for flagged rows: FB rows share one W pass.
__global__ __launch_bounds__(320) void fixup(
    const float* __restrict__ X, const float* __restrict__ W,
    const float* __restrict__ bq, const float* __restrict__ gum,
    const float* __restrict__ cv, float* __restrict__ out,
    const int* __restrict__ flags0, const int* __restrict__ flags1,
    const int* __restrict__ cnt)
{
    __shared__ float xs[FB][HID];
    __shared__ float vals[FB][CC];
    __shared__ int stok[FB];
    const int tid = threadIdx.x;
    const int n0 = cnt[0], n1 = cnt[1];
    const int nb0 = (n0 + FB - 1) / FB;
    const int nb1 = (n1 + FB - 1) / FB;

    for (int bb = blockIdx.x; bb < nb0 + nb1; bb += gridDim.x) {
        const int g    = (bb < nb0) ? 0 : 1;
        const int lb   = (bb < nb0) ? bb : bb - nb0;
        const int n    = g ? n1 : n0;
        const int* fl  = g ? flags1 : flags0;
        const int r0   = lb * FB;
        const int nr   = (n - r0 < FB) ? (n - r0) : FB;

        if (tid < FB) {
            int idx = r0 + tid;
            if (idx >= n) idx = n - 1;
            stok[tid] = fl[idx];
        }
        __syncthreads();
        for (int i = tid; i < FB * (HID / 4); i += 320) {
            int r = i >> 7, k4 = i & 127;
            *(float4*)&xs[r][k4 * 4] = *(const float4*)(X + (size_t)stok[r] * HID + k4 * 4);
        }
        __syncthreads();

        {
            const int c = tid;
            if (c < CC) {
                const float* wr = W + (size_t)(g * CC + c) * HID;
                float acc[FB];
#pragma unroll
                for (int r = 0; r < FB; ++r) acc[r] = 0.f;
                for (int k4 = 0; k4 < HID / 4; ++k4) {
                    float4 w4 = *(const float4*)(wr + k4 * 4);
#pragma unroll
                    for (int r = 0; r < FB; ++r) {
                        float4 xv = *(const float4*)&xs[r][k4 * 4];
                        acc[r] = fmaf(xv.x, w4.x, acc[r]);
                        acc[r] = fmaf(xv.y, w4.y, acc[r]);
                        acc[r] = fmaf(xv.z, w4.z, acc[r]);
                        acc[r] = fmaf(xv.w, w4.w, acc[r]);
                    }
                }
                float bias = bq[g * CC + c];
#pragma unroll
                for (int r = 0; r < FB; ++r)
                    vals[r][c] = acc[r] + bias + gum[((size_t)stok[r] * GG + g) * CC + c];
            }
        }
        __syncthreads();

        const int lane = tid & 63;
        const int wvv  = tid >> 6;
        if (wvv < FB) {
            const int r = wvv;
            if (r < nr) {
                float b = -3.0e38f; int bi = 0;
#pragma unroll
                for (int j = 0; j < 5; ++j) {
                    int c = lane + j * 64;
                    float v = vals[r][c];
                    if (v > b || (v == b && c < bi)) { b = v; bi = c; }
                }
#pragma unroll
                for (int m = 32; m; m >>= 1) {
                    float ob = __shfl_xor(b, m, 64);
                    int  obi = __shfl_xor(bi, m, 64);
                    if (ob > b || (ob == b && obi < bi)) { b = ob; bi = obi; }
                }
                int tok = stok[r];
                float2 cvv = *(const float2*)(cv + ((size_t)(g * CC + bi)) * DHALF + lane * 2);
                *(float2*)(out + (size_t)tok * 256 + g * DHALF + lane * 2) = cvv;
            }
        }
        __syncthreads();
    }
}

__global__ __launch_bounds__(256) void perpk(
    const float* __restrict__ meanAcc, float* __restrict__ outp, int ntot)
{
    __shared__ float red0[256];
    __shared__ float red1[256];
    const float invn = 1.f / (float)ntot;
    float h0 = 0.f, h1 = 0.f;
    for (int c = threadIdx.x; c < CC; c += 256) {
        float p0 = meanAcc[c]      * invn;
        float p1 = meanAcc[CC + c] * invn;
        h0 -= p0 * logf(p0 + 1e-7f);
        h1 -= p1 * logf(p1 + 1e-7f);
    }
    red0[threadIdx.x] = h0; red1[threadIdx.x] = h1;
    __syncthreads();
    for (int s = 128; s; s >>= 1) {
        if (threadIdx.x < (unsigned)s) {
            red0[threadIdx.x] += red0[threadIdx.x + s];
            red1[threadIdx.x] += red1[threadIdx.x + s];
        }
        __syncthreads();
    }
    if (threadIdx.x == 0) outp[0] = expf(red0[0]) + expf(red1[0]);
}

extern "C" void kernel_launch(void* const* d_in, const int* in_sizes, int n_in,
                              void* d_out, int out_size, void* d_ws, size_t ws_size,
                              hipStream_t stream) {
    const float* x      = (const float*)d_in[0];
    const float* gumbel = (const float*)d_in[1];
    const float* Wq     = (const float*)d_in[2];
    const float* bq     = (const float*)d_in[3];
    const float* cv     = (const float*)d_in[4];
    float* out = (float*)d_out;

    const int NT = in_sizes[0] / HID;       // 32768 tokens

    char* wsc = (char*)d_ws;
    float* meanAcc = (float*)wsc;                          // 640 f
    int*   cnt     = (int*)(wsc + 2560);                   // 2 ints
    int*   flags0  = (int*)(wsc + 4096);                   // 32768 ints
    int*   flags1  = (int*)(wsc + 135168);                 // 32768 ints
    unsigned short* Wpk = (unsigned short*)(wsc + 266240); // 640*512 f16 packed

    zero_misc<<<1, 256, 0, stream>>>(meanAcc, cnt);
    pack_w<<<160, 256, 0, stream>>>(Wq, Wpk);

    const int nwg = (NT / 64) * 2;          // 1024 blocks = 4/CU at 4 waves each
    fused<<<nwg, 256, 0, stream>>>(x, Wpk, bq, gumbel, cv, out,
                                   meanAcc, cnt, flags0, flags1);

    fixup<<<256, 320, 0, stream>>>(x, Wq, bq, gumbel, cv, out, flags0, flags1, cnt);
    perpk<<<1, 256, 0, stream>>>(meanAcc, out + (size_t)out_size - 1, NT);
}

// Round 12
// 145.020 us; speedup vs baseline: 1.1508x; 1.1508x over previous
//
#include <hip/hip_runtime.h>
#include <hip/hip_fp16.h>

#define HID 512
#define GC  640
#define CC  320
#define GG  2
#define DHALF 128
#define MARGIN 0.004f
#define FB 4

typedef __attribute__((ext_vector_type(8))) _Float16 half8;
typedef __attribute__((ext_vector_type(4))) float float4v;

__global__ __launch_bounds__(256) void zero_misc(float* meanAcc, int* cnt) {
    for (int i = threadIdx.x; i < GC; i += 256) meanAcc[i] = 0.f;
    if (threadIdx.x < 2) cnt[threadIdx.x] = 0;
}

// Pack W (fp32 [640][512]) into fp16 MFMA-frag order:
// frag t=(g*320 + kk*20 + j): lane l holds W[g*320+j*16+(l&15)][kk*32+(l>>4)*8 ..+7]
// stored contiguously at Wpk + t*512 + l*8  -> B-frag load = coalesced 1KB.
__global__ __launch_bounds__(256) void pack_w(
    const float* __restrict__ W, unsigned short* __restrict__ Wpk)
{
    const int t    = blockIdx.x * 4 + (threadIdx.x >> 6);   // 0..639
    const int lane = threadIdx.x & 63;
    const int g = t / 320, rem = t % 320, kk = rem / 20, j = rem % 20;
    const int row = g * 320 + j * 16 + (lane & 15);
    const int k   = kk * 32 + (lane >> 4) * 8;
    const float* src = W + (size_t)row * HID + k;
    float4 xa = *(const float4*)src;
    float4 xb = *(const float4*)(src + 4);
    half8 h;
    h[0] = (_Float16)xa.x; h[1] = (_Float16)xa.y;
    h[2] = (_Float16)xa.z; h[3] = (_Float16)xa.w;
    h[4] = (_Float16)xb.x; h[5] = (_Float16)xb.y;
    h[6] = (_Float16)xb.z; h[7] = (_Float16)xb.w;
    *(half8*)(Wpk + (size_t)t * 512 + lane * 8) = h;
}

// Barrier-free wave-autonomous fused kernel (round-11 structure, epilogue
// r-loop FORCE-UNROLLED so every acc[j][r] index is compile-time constant:
// rule #20 — runtime-indexed ext_vector arrays go to scratch).
__global__ __launch_bounds__(256, 4) void fused(
    const float* __restrict__ X, const unsigned short* __restrict__ Wpk,
    const float* __restrict__ bq, const float* __restrict__ gum,
    const float* __restrict__ cv, float* __restrict__ out,
    float* __restrict__ meanAcc, int* __restrict__ cnt,
    int* __restrict__ flags0, int* __restrict__ flags1)
{
    __shared__ float rep[4][4][328];    // [wave][token-slot][padded cols] 21KB
    __shared__ float bqs[CC];
    __shared__ float smean[CC];

    const int tid  = threadIdx.x;
    const int lane = tid & 63;
    const int wv   = tid >> 6;          // 0..3
    const int lq   = lane & 15;
    const int q    = lane >> 4;

    int bid = blockIdx.x, nwg = gridDim.x;
    int swz = ((nwg & 7) == 0) ? (bid & 7) * (nwg >> 3) + (bid >> 3) : bid;
    const int g    = swz & 1;
    const int tok0 = (swz >> 1) * 64 + wv * 16;     // wave's token base
    int* flagsg = g ? flags1 : flags0;

    for (int i = tid; i < CC; i += 256) { bqs[i] = bq[g * CC + i]; smean[i] = 0.f; }
    __syncthreads();

    // A: lane reads X[tok0+lq][kk*32 + q*8 ..+7] (fp32)
    const float* xsrc = X + (size_t)(tok0 + lq) * HID + q * 8;
    // B: packed frags for this group
    const unsigned short* bsrc = Wpk + (size_t)g * 163840 + lane * 8;

    float4v acc[20];
#pragma unroll
    for (int j = 0; j < 20; ++j) acc[j] = (float4v){0.f, 0.f, 0.f, 0.f};

    for (int ko = 0; ko < 4; ++ko) {
#pragma unroll
        for (int ki = 0; ki < 4; ++ki) {
            const int kk = ko * 4 + ki;
            float4 xa = *(const float4*)(xsrc + kk * 32);
            float4 xb = *(const float4*)(xsrc + kk * 32 + 4);
            half8 a;
            a[0] = (_Float16)xa.x; a[1] = (_Float16)xa.y;
            a[2] = (_Float16)xa.z; a[3] = (_Float16)xa.w;
            a[4] = (_Float16)xb.x; a[5] = (_Float16)xb.y;
            a[6] = (_Float16)xb.z; a[7] = (_Float16)xb.w;
            const unsigned short* bk = bsrc + kk * 10240;
#pragma unroll
            for (int j = 0; j < 20; ++j) {
                half8 b = *(const half8*)(bk + j * 512);
                acc[j] = __builtin_amdgcn_mfma_f32_16x16x32_f16(a, b, acc[j], 0, 0, 0);
            }
        }
        __syncthreads();   // drift control: keeps the 4 waves' B streams L1-coherent
    }

    // ---- epilogue (wave-local), r FORCE-UNROLLED (static acc indices) ----
    float macc[20];
#pragma unroll
    for (int j = 0; j < 20; ++j) macc[j] = 0.f;
    const int cb = lq * 20;

#pragma unroll
    for (int r = 0; r < 4; ++r) {
        // phase A: lane (q,lq) owns token q*4+r; scatter its 20 cols
#pragma unroll
        for (int j = 0; j < 20; ++j)
            rep[wv][q][j * 16 + lq] = acc[j][r] + bqs[j * 16 + lq];
        asm volatile("s_waitcnt lgkmcnt(0)" ::: "memory");   // wave-local fence

        // phase B: lane -> token-slot q, contiguous codes cb..cb+19
        const int tglob = tok0 + q * 4 + r;
        const float* rrow = &rep[wv][q][cb];
        const float* grow = gum + ((size_t)tglob * GG + g) * CC + cb;

        float s = 0.f;
        float b = -3.0e38f; int bi = 0; float s2 = -3.0e38f;
#pragma unroll
        for (int jj = 0; jj < 5; ++jj) {
            float4 lv = *(const float4*)(rrow + jj * 4);
            float4 gv = *(const float4*)(grow + jj * 4);
            float lf[4] = {lv.x, lv.y, lv.z, lv.w};
            float gf[4] = {gv.x, gv.y, gv.z, gv.w};
#pragma unroll
            for (int t = 0; t < 4; ++t) {
                float v = lf[t] + gf[t];
                if (v > b)       { s2 = b; b = v; bi = cb + jj * 4 + t; }
                else if (v > s2) { s2 = v; }
                s += __expf(lf[t]);
            }
        }
        // fused 4-step reduce within the 16-lane token group
#pragma unroll
        for (int m = 1; m < 16; m <<= 1) {
            float os  = __shfl_xor(s,  m, 64);
            float ob  = __shfl_xor(b,  m, 64);
            int   obi = __shfl_xor(bi, m, 64);
            float os2 = __shfl_xor(s2, m, 64);
            s += os;
            if (ob > b || (ob == b && obi < bi)) { s2 = fmaxf(os2, b); b = ob; bi = obi; }
            else                                 { s2 = fmaxf(s2, ob); }
        }
        float inv = 1.f / s;
        // second pass from LDS (keeps live regs low)
#pragma unroll
        for (int jj = 0; jj < 5; ++jj) {
            float4 lv = *(const float4*)(rrow + jj * 4);
            macc[jj*4+0] += __expf(lv.x) * inv;
            macc[jj*4+1] += __expf(lv.y) * inv;
            macc[jj*4+2] += __expf(lv.z) * inv;
            macc[jj*4+3] += __expf(lv.w) * inv;
        }

        if (lq == 0 && (b - s2) < MARGIN) {
            int p = atomicAdd(&cnt[g], 1);
            flagsg[p] = tglob;
        }
        const float* cvp = cv + ((size_t)(g * CC + bi)) * DHALF + lq * 8;
        float4 c0v = *(const float4*)cvp;
        float4 c1v = *(const float4*)(cvp + 4);
        float* op = out + (size_t)tglob * 256 + g * DHALF + lq * 8;
        *(float4*)op       = c0v;
        *(float4*)(op + 4) = c1v;
        asm volatile("s_waitcnt lgkmcnt(0)" ::: "memory");   // reads done before overwrite
    }

    // fold macc across token-slots (q), then block smean, then global
#pragma unroll
    for (int j = 0; j < 20; ++j) {
        macc[j] += __shfl_xor(macc[j], 16, 64);
        macc[j] += __shfl_xor(macc[j], 32, 64);
    }
    if (lane < 16) {
#pragma unroll
        for (int j = 0; j < 20; ++j)
            atomicAdd(&smean[cb + j], macc[j]);
    }
    __syncthreads();
    for (int i = tid; i < CC; i += 256)
        atomicAdd(&meanAcc[g * CC + i], smean[i]);
}

// Exact fp32 recompute for flagged rows: FB rows share one W pass.
__global__ __launch_bounds__(320) void fixup(
    const float* __restrict__ X, const float* __restrict__ W,
    const float* __restrict__ bq, const float* __restrict__ gum,
    const float* __restrict__ cv, float* __restrict__ out,
    const int* __restrict__ flags0, const int* __restrict__ flags1,
    const int* __restrict__ cnt)
{
    __shared__ float xs[FB][HID];
    __shared__ float vals[FB][CC];
    __shared__ int stok[FB];
    const int tid = threadIdx.x;
    const int n0 = cnt[0], n1 = cnt[1];
    const int nb0 = (n0 + FB - 1) / FB;
    const int nb1 = (n1 + FB - 1) / FB;

    for (int bb = blockIdx.x; bb < nb0 + nb1; bb += gridDim.x) {
        const int g    = (bb < nb0) ? 0 : 1;
        const int lb   = (bb < nb0) ? bb : bb - nb0;
        const int n    = g ? n1 : n0;
        const int* fl  = g ? flags1 : flags0;
        const int r0   = lb * FB;
        const int nr   = (n - r0 < FB) ? (n - r0) : FB;

        if (tid < FB) {
            int idx = r0 + tid;
            if (idx >= n) idx = n - 1;
            stok[tid] = fl[idx];
        }
        __syncthreads();
        for (int i = tid; i < FB * (HID / 4); i += 320) {
            int r = i >> 7, k4 = i & 127;
            *(float4*)&xs[r][k4 * 4] = *(const float4*)(X + (size_t)stok[r] * HID + k4 * 4);
        }
        __syncthreads();

        {
            const int c = tid;
            if (c < CC) {
                const float* wr = W + (size_t)(g * CC + c) * HID;
                float acc[FB];
#pragma unroll
                for (int r = 0; r < FB; ++r) acc[r] = 0.f;
                for (int k4 = 0; k4 < HID / 4; ++k4) {
                    float4 w4 = *(const float4*)(wr + k4 * 4);
#pragma unroll
                    for (int r = 0; r < FB; ++r) {
                        float4 xv = *(const float4*)&xs[r][k4 * 4];
                        acc[r] = fmaf(xv.x, w4.x, acc[r]);
                        acc[r] = fmaf(xv.y, w4.y, acc[r]);
                        acc[r] = fmaf(xv.z, w4.z, acc[r]);
                        acc[r] = fmaf(xv.w, w4.w, acc[r]);
                    }
                }
                float bias = bq[g * CC + c];
#pragma unroll
                for (int r = 0; r < FB; ++r)
                    vals[r][c] = acc[r] + bias + gum[((size_t)stok[r] * GG + g) * CC + c];
            }
        }
        __syncthreads();

        const int lane = tid & 63;
        const int wvv  = tid >> 6;
        if (wvv < FB) {
            const int r = wvv;
            if (r < nr) {
                float b = -3.0e38f; int bi = 0;
#pragma unroll
                for (int j = 0; j < 5; ++j) {
                    int c = lane + j * 64;
                    float v = vals[r][c];
                    if (v > b || (v == b && c < bi)) { b = v; bi = c; }
                }
#pragma unroll
                for (int m = 32; m; m >>= 1) {
                    float ob = __shfl_xor(b, m, 64);
                    int  obi = __shfl_xor(bi, m, 64);
                    if (ob > b || (ob == b && obi < bi)) { b = ob; bi = obi; }
                }
                int tok = stok[r];
                float2 cvv = *(const float2*)(cv + ((size_t)(g * CC + bi)) * DHALF + lane * 2);
                *(float2*)(out + (size_t)tok * 256 + g * DHALF + lane * 2) = cvv;
            }
        }
        __syncthreads();
    }
}

__global__ __launch_bounds__(256) void perpk(
    const float* __restrict__ meanAcc, float* __restrict__ outp, int ntot)
{
    __shared__ float red0[256];
    __shared__ float red1[256];
    const float invn = 1.f / (float)ntot;
    float h0 = 0.f, h1 = 0.f;
    for (int c = threadIdx.x; c < CC; c += 256) {
        float p0 = meanAcc[c]      * invn;
        float p1 = meanAcc[CC + c] * invn;
        h0 -= p0 * logf(p0 + 1e-7f);
        h1 -= p1 * logf(p1 + 1e-7f);
    }
    red0[threadIdx.x] = h0; red1[threadIdx.x] = h1;
    __syncthreads();
    for (int s = 128; s; s >>= 1) {
        if (threadIdx.x < (unsigned)s) {
            red0[threadIdx.x] += red0[threadIdx.x + s];
            red1[threadIdx.x] += red1[threadIdx.x + s];
        }
        __syncthreads();
    }
    if (threadIdx.x == 0) outp[0] = expf(red0[0]) + expf(red1[0]);
}

extern "C" void kernel_launch(void* const* d_in, const int* in_sizes, int n_in,
                              void* d_out, int out_size, void* d_ws, size_t ws_size,
                              hipStream_t stream) {
    const float* x      = (const float*)d_in[0];
    const float* gumbel = (const float*)d_in[1];
    const float* Wq     = (const float*)d_in[2];
    const float* bq     = (const float*)d_in[3];
    const float* cv     = (const float*)d_in[4];
    float* out = (float*)d_out;

    const int NT = in_sizes[0] / HID;       // 32768 tokens

    char* wsc = (char*)d_ws;
    float* meanAcc = (float*)wsc;                          // 640 f
    int*   cnt     = (int*)(wsc + 2560);                   // 2 ints
    int*   flags0  = (int*)(wsc + 4096);                   // 32768 ints
    int*   flags1  = (int*)(wsc + 135168);                 // 32768 ints
    unsigned short* Wpk = (unsigned short*)(wsc + 266240); // 640*512 f16 packed

    zero_misc<<<1, 256, 0, stream>>>(meanAcc, cnt);
    pack_w<<<160, 256, 0, stream>>>(Wq, Wpk);

    const int nwg = (NT / 64) * 2;          // 1024 blocks = 4/CU at 4 waves each
    fused<<<nwg, 256, 0, stream>>>(x, Wpk, bq, gumbel, cv, out,
                                   meanAcc, cnt, flags0, flags1);

    fixup<<<256, 320, 0, stream>>>(x, Wq, bq, gumbel, cv, out, flags0, flags1, cnt);
    perpk<<<1, 256, 0, stream>>>(meanAcc, out + (size_t)out_size - 1, NT);
}